// Round 1
// 634.777 us; speedup vs baseline: 1.0164x; 1.0164x over previous
//
#include <hip/hip_runtime.h>
#include <hip/hip_bf16.h>

#define TOTALROWS 262144
#define NSEG      1024
#define SEGROWS   256
#define HD        64
#define DEMB      32
#define DPRE      96
#define N1        512
#define N2        1024
#define EPSB      1e-5f

typedef short s16x8 __attribute__((ext_vector_type(8)));
typedef float f32x4 __attribute__((ext_vector_type(4)));

static __device__ __forceinline__ ushort f2bf(float x) {
    union { float f; unsigned u; } v; v.f = x;
    unsigned r = v.u + 0x7FFFu + ((v.u >> 16) & 1u);   // round-to-nearest-even
    return (ushort)(r >> 16);
}

// async global->LDS, 16B per lane; LDS dest = wave-uniform base + lane*16
static __device__ __forceinline__ void gload_lds16(const void* g, void* l) {
    __builtin_amdgcn_global_load_lds(
        (const __attribute__((address_space(1))) void*)g,
        (__attribute__((address_space(3))) void*)l, 16, 0, 0);
}

// ---------------- W2 f32 -> bf16 (canonical row-major) ----------------
__global__ void convert_w2_kernel(const float* __restrict__ w2, ushort* __restrict__ w2b) {
    int i = blockIdx.x * 256 + threadIdx.x;      // quad id over N2*N1/4 = 131072
    float4 v = ((const float4*)w2)[i];
    ushort4 o;
    o.x = f2bf(v.x); o.y = f2bf(v.y); o.z = f2bf(v.z); o.w = f2bf(v.w);
    ((ushort4*)w2b)[i] = o;
}

// ---------------- layer 1: mlp_in @ W1^T -> segBN -> relu -> h1 (bf16) ----------------
// grid: (1024 segs, 2 col-tiles of 256), block 512 (8 waves, 2x4), wave tile 128x64
// LDS pad 96->104 ushorts gives 2-way (free) bank access: no swizzle needed here.
__global__ __launch_bounds__(512, 2) void layer1_kernel(
    const float* __restrict__ hstate, const float* __restrict__ ebpr,
    const float* __restrict__ Wsp, const float* __restrict__ W1,
    const float* __restrict__ g1, const float* __restrict__ be1,
    ushort* __restrict__ h1)
{
    __shared__ __align__(16) ushort As[SEGROWS * 104];   // mlp_in tile [256][96] pad->104
    __shared__ __align__(16) ushort Bs[SEGROWS * 104];   // W1 tile     [256][96] pad->104
    __shared__ float statsS[8][4][16];
    __shared__ float statsQ[8][4][16];

    const int seg  = blockIdx.x;
    const int ct   = blockIdx.y;
    const int tid  = threadIdx.x;
    const int lane = tid & 63, wid = tid >> 6;
    const int wr   = wid >> 2, wc = wid & 3;

    // --- build A tile: cols 0..31 = rel_emb, cols 32..95 = h_state ---
    {
        const float4* hs4 = (const float4*)(hstate + (size_t)seg * SEGROWS * HD);
        #pragma unroll
        for (int i = 0; i < 8; ++i) {
            int u = tid + i * 512;                 // 4096 quads
            int r = u >> 4, c4 = u & 15;
            float4 v = hs4[u];
            ushort* dst = &As[r * 104 + DEMB + c4 * 4];
            dst[0] = f2bf(v.x); dst[1] = f2bf(v.y); dst[2] = f2bf(v.z); dst[3] = f2bf(v.w);
        }
        #pragma unroll
        for (int i = 0; i < 16; ++i) {
            int u = tid + i * 512;                 // 8192 outputs
            int r = u >> 5, k = u & 31;
            float4 e = ((const float4*)ebpr)[seg * SEGROWS + r];
            float4 w = ((const float4*)Wsp)[k];
            // pos = [e0, e2, e1, e3] (transpose (0,2,1) of (2,BF))
            float val = w.x * e.x + w.y * e.z + w.z * e.y + w.w * e.w;
            As[r * 104 + k] = f2bf(val);           // b_sp cancels through segment BN
        }
    }
    // --- B tile: W1 rows ct*256 .. +256, 96 cols ---
    {
        const float4* w14 = (const float4*)(W1 + (size_t)ct * 256 * DPRE);
        #pragma unroll
        for (int i = 0; i < 12; ++i) {
            int u = tid + i * 512;                 // 6144 quads
            int r = u / 24, c4 = u % 24;
            float4 v = w14[u];
            ushort* dst = &Bs[r * 104 + c4 * 4];
            dst[0] = f2bf(v.x); dst[1] = f2bf(v.y); dst[2] = f2bf(v.z); dst[3] = f2bf(v.w);
        }
    }
    __syncthreads();

    f32x4 acc[8][4] = {};
    const int arow0 = wr * 128 + (lane & 15);
    const int bcol0 = wc * 64  + (lane & 15);
    const int kg    = (lane >> 4) * 8;
    #pragma unroll
    for (int ks = 0; ks < 3; ++ks) {
        s16x8 af[8], bfr[4];
        #pragma unroll
        for (int m = 0; m < 8; ++m)
            af[m] = *(const s16x8*)&As[(arow0 + m * 16) * 104 + ks * 32 + kg];
        #pragma unroll
        for (int n = 0; n < 4; ++n)
            bfr[n] = *(const s16x8*)&Bs[(bcol0 + n * 16) * 104 + ks * 32 + kg];
        #pragma unroll
        for (int m = 0; m < 8; ++m)
            #pragma unroll
            for (int n = 0; n < 4; ++n)
                acc[m][n] = __builtin_amdgcn_mfma_f32_16x16x32_bf16(af[m], bfr[n], acc[m][n], 0, 0, 0);
    }

    // --- per-column stats over the 256 segment rows ---
    float s[4], q[4];
    #pragma unroll
    for (int n = 0; n < 4; ++n) { s[n] = 0.f; q[n] = 0.f; }
    #pragma unroll
    for (int m = 0; m < 8; ++m)
        #pragma unroll
        for (int n = 0; n < 4; ++n)
            #pragma unroll
            for (int j = 0; j < 4; ++j) { float v = acc[m][n][j]; s[n] += v; q[n] += v * v; }
    #pragma unroll
    for (int n = 0; n < 4; ++n) {
        s[n] += __shfl_xor(s[n], 16); q[n] += __shfl_xor(q[n], 16);
        s[n] += __shfl_xor(s[n], 32); q[n] += __shfl_xor(q[n], 32);
    }
    if ((lane >> 4) == 0) {
        #pragma unroll
        for (int n = 0; n < 4; ++n) { statsS[wid][n][lane] = s[n]; statsQ[wid][n][lane] = q[n]; }
    }
    __syncthreads();

    const float inv256 = 1.0f / 256.0f;
    float aa[4], bb[4];
    const int c16 = lane & 15;
    #pragma unroll
    for (int n = 0; n < 4; ++n) {
        float sum = statsS[wc][n][c16] + statsS[4 + wc][n][c16];
        float sq  = statsQ[wc][n][c16] + statsQ[4 + wc][n][c16];
        float mean = sum * inv256;
        float var  = sq * inv256 - mean * mean;
        float rinv = rsqrtf(var + EPSB);
        int col = ct * 256 + wc * 64 + n * 16 + c16;
        aa[n] = g1[col] * rinv;
        bb[n] = be1[col] - mean * aa[n];
    }

    ushort* outp = h1 + (size_t)(seg * SEGROWS) * N1 + ct * 256;
    const int rbase = wr * 128 + (lane >> 4) * 4;
    #pragma unroll
    for (int m = 0; m < 8; ++m)
        #pragma unroll
        for (int j = 0; j < 4; ++j) {
            int r = rbase + m * 16 + j;
            ushort* rowp = outp + (size_t)r * N1 + wc * 64 + c16;
            #pragma unroll
            for (int n = 0; n < 4; ++n) {
                float v = acc[m][n][j] * aa[n] + bb[n];
                v = v > 0.f ? v : 0.f;
                rowp[n * 16] = f2bf(v);
            }
        }
}

// ---------------- layer 2 helpers (BK=32, XOR-swizzled LDS) ----------------
// LDS tiles are [256 rows][64 B]; each row = 4 chunks of 16 B.
// Swizzle: physical_chunk = logical_chunk ^ ((row>>1)&3).
// Unswizzled, a quarter-wave's ds_read_b128 hits one chunk column ->
// 8 lanes per bank-quad = 8-way conflict (~2.9x, m136). Swizzled: 2-way = free.
// global_load_lds writes linearly (rule #21), so the swizzle is applied as the
// INVERSE permutation on the per-lane GLOBAL source chunk (m173 pattern), and
// the forward XOR on the ds_read offset. Same bytes move; numerics identical.

// stage step t (k window [t*32, t*32+32)) of A and B into LDS buffers.
// 4 gload_lds per wave (2 per matrix). Row stride in global = 1024B.
static __device__ __forceinline__ void stage_step(
    const char* gA, const char* gB, ushort* lA, ushort* lB,
    int t, int wid, int lane)
{
    const int rsub = lane >> 2;            // 16 rows per instruction group
    // dest row for this lane is (g*16 + rsub); f(row) = (rsub>>1)&3 = (lane>>3)&3.
    // lane writes physical chunk (lane&3), so it must fetch logical chunk
    // (lane&3) ^ f(row) from global.
    const int cb   = (((lane & 3) ^ ((lane >> 3) & 3)) << 4);
    #pragma unroll
    for (int i = 0; i < 2; ++i) {
        int g = i * 8 + wid;               // 0..15, each covers 16 rows
        size_t go = (size_t)(g * 16 + rsub) * 1024 + (size_t)t * 64 + cb;
        gload_lds16(gA + go, (char*)lA + g * 1024);
        gload_lds16(gB + go, (char*)lB + g * 1024);
    }
}

static __device__ __forceinline__ void compute_step(
    const ushort* lA, const ushort* lB, f32x4 (&acc)[8][4],
    int arow0, int bcol0, int swz)
{
    s16x8 af[8], bfr[4];
    #pragma unroll
    for (int m = 0; m < 8; ++m)
        af[m] = *(const s16x8*)&lA[(arow0 + m * 16) * 32 + swz];
    #pragma unroll
    for (int n = 0; n < 4; ++n)
        bfr[n] = *(const s16x8*)&lB[(bcol0 + n * 16) * 32 + swz];
    __builtin_amdgcn_s_setprio(1);
    #pragma unroll
    for (int m = 0; m < 8; ++m)
        #pragma unroll
        for (int n = 0; n < 4; ++n)
            acc[m][n] = __builtin_amdgcn_mfma_f32_16x16x32_bf16(af[m], bfr[n], acc[m][n], 0, 0, 0);
    __builtin_amdgcn_s_setprio(0);
}

// ---------------- layer 2: h1 @ W2^T -> segBN -> relu -> out (f32) ----------------
// grid: 4096 blocks XCD-swizzled; block 512 (8 waves, 2x4); tile 256x256;
// K=512 as 16 steps of BK=32; 4 LDS buffers, lead-3 staging, counted vmcnt.
__global__ __launch_bounds__(512, 2) void layer2_kernel(
    const ushort* __restrict__ h1, const ushort* __restrict__ W2b,
    const float* __restrict__ g2, const float* __restrict__ be2,
    float* __restrict__ out)
{
    __shared__ __align__(16) ushort As[4][SEGROWS * 32];  // 4 x 16 KiB
    __shared__ __align__(16) ushort Bs[4][256 * 32];      // 4 x 16 KiB
    __shared__ float statsS[8][4][16];
    __shared__ float statsQ[8][4][16];

    // bijective XCD swizzle (nwg=4096 % 8 == 0): the 4 ct-blocks of a segment
    // run consecutively on one XCD -> h1 panel (256KB) hits L2 3 of 4 times.
    const int b   = blockIdx.x;
    const int wg  = (b & 7) * 512 + (b >> 3);
    const int seg = wg >> 2;
    const int ct  = wg & 3;

    const int tid  = threadIdx.x;
    const int lane = tid & 63, wid = tid >> 6;
    const int wr   = wid >> 2, wc = wid & 3;

    const char* srcA = (const char*)(h1  + (size_t)seg * SEGROWS * N1);
    const char* srcB = (const char*)(W2b + (size_t)ct  * 256    * N1);

    f32x4 acc[8][4] = {};
    const int arow0 = wr * 128 + (lane & 15);
    const int bcol0 = wc * 64  + (lane & 15);
    // logical chunk = lane>>4 (16B k-chunk); row-dependent part of the XOR is
    // lane-constant for all fragment rows (row = const + (lane&15) + 16m):
    // f(row) = ((lane&15)>>1)&3 = (lane>>1)&3. ushort offset = chunk*8.
    const int swz  = (((lane >> 4) ^ ((lane >> 1) & 3)) << 3);

    // prologue: stage steps 0,1,2 (12 loads/wave in flight)
    stage_step(srcA, srcB, As[0], Bs[0], 0, wid, lane);
    stage_step(srcA, srcB, As[1], Bs[1], 1, wid, lane);
    stage_step(srcA, srcB, As[2], Bs[2], 2, wid, lane);

    // per step: stage t+3 | wait own loads of step t (3 steps = 12 in flight)
    //           | barrier (all waves' step-t loads landed) | ds_read+MFMA
    //           | barrier (all reads of buf t&3 done before step t+4 restage)
#define L2_STEP(T, VW)                                                           \
    {                                                                            \
        if ((T) + 3 < 16)                                                        \
            stage_step(srcA, srcB, As[((T)+3)&3], Bs[((T)+3)&3], (T)+3, wid, lane); \
        asm volatile("s_waitcnt vmcnt(" #VW ")" ::: "memory");                   \
        __builtin_amdgcn_s_barrier();                                            \
        compute_step(As[(T)&3], Bs[(T)&3], acc, arow0, bcol0, swz);              \
        __builtin_amdgcn_s_barrier();                                            \
    }

    L2_STEP(0, 12)  L2_STEP(1, 12)  L2_STEP(2, 12)  L2_STEP(3, 12)
    L2_STEP(4, 12)  L2_STEP(5, 12)  L2_STEP(6, 12)  L2_STEP(7, 12)
    L2_STEP(8, 12)  L2_STEP(9, 12)  L2_STEP(10, 12) L2_STEP(11, 12)
    L2_STEP(12, 12) L2_STEP(13, 8)  L2_STEP(14, 4)  L2_STEP(15, 0)
#undef L2_STEP

    // --- per-column stats over the 256 segment rows ---
    float s[4], q[4];
    #pragma unroll
    for (int n = 0; n < 4; ++n) { s[n] = 0.f; q[n] = 0.f; }
    #pragma unroll
    for (int m = 0; m < 8; ++m)
        #pragma unroll
        for (int n = 0; n < 4; ++n)
            #pragma unroll
            for (int j = 0; j < 4; ++j) { float v = acc[m][n][j]; s[n] += v; q[n] += v * v; }
    #pragma unroll
    for (int n = 0; n < 4; ++n) {
        s[n] += __shfl_xor(s[n], 16); q[n] += __shfl_xor(q[n], 16);
        s[n] += __shfl_xor(s[n], 32); q[n] += __shfl_xor(q[n], 32);
    }
    if ((lane >> 4) == 0) {
        #pragma unroll
        for (int n = 0; n < 4; ++n) { statsS[wid][n][lane] = s[n]; statsQ[wid][n][lane] = q[n]; }
    }
    __syncthreads();

    const float inv256 = 1.0f / 256.0f;
    float aa[4], bb[4];
    const int c16 = lane & 15;
    #pragma unroll
    for (int n = 0; n < 4; ++n) {
        float sum = statsS[wc][n][c16] + statsS[4 + wc][n][c16];
        float sq  = statsQ[wc][n][c16] + statsQ[4 + wc][n][c16];
        float mean = sum * inv256;
        float var  = sq * inv256 - mean * mean;
        float rinv = rsqrtf(var + EPSB);
        int col = ct * 256 + wc * 64 + n * 16 + c16;
        aa[n] = g2[col] * rinv;
        bb[n] = be2[col] - mean * aa[n];
    }

    float* outp = out + (size_t)(seg * SEGROWS) * N2 + ct * 256;
    const int rbase = wr * 128 + (lane >> 4) * 4;
    #pragma unroll
    for (int m = 0; m < 8; ++m)
        #pragma unroll
        for (int j = 0; j < 4; ++j) {
            int r = rbase + m * 16 + j;
            float* rowp = outp + (size_t)r * N2 + wc * 64 + c16;
            #pragma unroll
            for (int n = 0; n < 4; ++n) {
                float v = acc[m][n][j] * aa[n] + bb[n];
                v = v > 0.f ? v : 0.f;
                rowp[n * 16] = v;
            }
        }
}

extern "C" void kernel_launch(void* const* d_in, const int* in_sizes, int n_in,
                              void* d_out, int out_size, void* d_ws, size_t ws_size,
                              hipStream_t stream) {
    const float* hstate = (const float*)d_in[0];
    const float* ebpr   = (const float*)d_in[1];
    const float* Wsp    = (const float*)d_in[2];
    // d_in[3] = b_sp  : cancels through segment BN (exact)
    const float* W1     = (const float*)d_in[4];
    // d_in[5] = b1    : cancels through segment BN (exact)
    const float* g1     = (const float*)d_in[6];
    const float* be1    = (const float*)d_in[7];
    const float* W2     = (const float*)d_in[8];
    // d_in[9] = b2    : cancels through segment BN (exact)
    const float* g2     = (const float*)d_in[10];
    const float* be2    = (const float*)d_in[11];
    float* outp         = (float*)d_out;

    ushort* h1  = (ushort*)d_ws;                          // 262144 x 512 bf16 = 256 MiB
    ushort* W2b = h1 + (size_t)TOTALROWS * N1;            // 1024 x 512 bf16 = 1 MiB

    convert_w2_kernel<<<dim3((N2 * N1 / 4) / 256), dim3(256), 0, stream>>>(W2, W2b);
    layer1_kernel<<<dim3(NSEG, 2), dim3(512), 0, stream>>>(hstate, ebpr, Wsp, W1, g1, be1, h1);
    layer2_kernel<<<dim3(4096), dim3(512), 0, stream>>>(h1, W2b, g2, be2, outp);
}

// Round 3
// 603.719 us; speedup vs baseline: 1.0687x; 1.0514x over previous
//
#include <hip/hip_runtime.h>
#include <hip/hip_bf16.h>

#define TOTALROWS 262144
#define NSEG      1024
#define SEGROWS   256
#define HD        64
#define DEMB      32
#define DPRE      96
#define N1        512
#define N2        1024
#define EPSB      1e-5f

typedef short s16x8 __attribute__((ext_vector_type(8)));
typedef float f32x4 __attribute__((ext_vector_type(4)));

static __device__ __forceinline__ ushort f2bf(float x) {
    union { float f; unsigned u; } v; v.f = x;
    unsigned r = v.u + 0x7FFFu + ((v.u >> 16) & 1u);   // round-to-nearest-even
    return (ushort)(r >> 16);
}

// async global->LDS, 16B per lane; LDS dest = wave-uniform base + lane*16
static __device__ __forceinline__ void gload_lds16(const void* g, void* l) {
    __builtin_amdgcn_global_load_lds(
        (const __attribute__((address_space(1))) void*)g,
        (__attribute__((address_space(3))) void*)l, 16, 0, 0);
}

// ---------------- W2 f32 -> bf16 (canonical row-major) ----------------
__global__ void convert_w2_kernel(const float* __restrict__ w2, ushort* __restrict__ w2b) {
    int i = blockIdx.x * 256 + threadIdx.x;      // quad id over N2*N1/4 = 131072
    float4 v = ((const float4*)w2)[i];
    ushort4 o;
    o.x = f2bf(v.x); o.y = f2bf(v.y); o.z = f2bf(v.z); o.w = f2bf(v.w);
    ((ushort4*)w2b)[i] = o;
}

// ---------------- layer 1: mlp_in @ W1^T -> segBN -> relu -> h1 (bf16) ----------------
// grid: (1024 segs, 2 col-tiles of 256), block 512 (8 waves, 2x4), wave tile 128x64
// LDS pad 96->104 ushorts gives 2-way (free) bank access: no swizzle needed here.
__global__ __launch_bounds__(512, 2) void layer1_kernel(
    const float* __restrict__ hstate, const float* __restrict__ ebpr,
    const float* __restrict__ Wsp, const float* __restrict__ W1,
    const float* __restrict__ g1, const float* __restrict__ be1,
    ushort* __restrict__ h1)
{
    __shared__ __align__(16) ushort As[SEGROWS * 104];   // mlp_in tile [256][96] pad->104
    __shared__ __align__(16) ushort Bs[SEGROWS * 104];   // W1 tile     [256][96] pad->104
    __shared__ float statsS[8][4][16];
    __shared__ float statsQ[8][4][16];

    const int seg  = blockIdx.x;
    const int ct   = blockIdx.y;
    const int tid  = threadIdx.x;
    const int lane = tid & 63, wid = tid >> 6;
    const int wr   = wid >> 2, wc = wid & 3;

    // --- build A tile: cols 0..31 = rel_emb, cols 32..95 = h_state ---
    {
        const float4* hs4 = (const float4*)(hstate + (size_t)seg * SEGROWS * HD);
        #pragma unroll
        for (int i = 0; i < 8; ++i) {
            int u = tid + i * 512;                 // 4096 quads
            int r = u >> 4, c4 = u & 15;
            float4 v = hs4[u];
            ushort* dst = &As[r * 104 + DEMB + c4 * 4];
            dst[0] = f2bf(v.x); dst[1] = f2bf(v.y); dst[2] = f2bf(v.z); dst[3] = f2bf(v.w);
        }
        #pragma unroll
        for (int i = 0; i < 16; ++i) {
            int u = tid + i * 512;                 // 8192 outputs
            int r = u >> 5, k = u & 31;
            float4 e = ((const float4*)ebpr)[seg * SEGROWS + r];
            float4 w = ((const float4*)Wsp)[k];
            // pos = [e0, e2, e1, e3] (transpose (0,2,1) of (2,BF))
            float val = w.x * e.x + w.y * e.z + w.z * e.y + w.w * e.w;
            As[r * 104 + k] = f2bf(val);           // b_sp cancels through segment BN
        }
    }
    // --- B tile: W1 rows ct*256 .. +256, 96 cols ---
    {
        const float4* w14 = (const float4*)(W1 + (size_t)ct * 256 * DPRE);
        #pragma unroll
        for (int i = 0; i < 12; ++i) {
            int u = tid + i * 512;                 // 6144 quads
            int r = u / 24, c4 = u % 24;
            float4 v = w14[u];
            ushort* dst = &Bs[r * 104 + c4 * 4];
            dst[0] = f2bf(v.x); dst[1] = f2bf(v.y); dst[2] = f2bf(v.z); dst[3] = f2bf(v.w);
        }
    }
    __syncthreads();

    f32x4 acc[8][4] = {};
    const int arow0 = wr * 128 + (lane & 15);
    const int bcol0 = wc * 64  + (lane & 15);
    const int kg    = (lane >> 4) * 8;
    #pragma unroll
    for (int ks = 0; ks < 3; ++ks) {
        s16x8 af[8], bfr[4];
        #pragma unroll
        for (int m = 0; m < 8; ++m)
            af[m] = *(const s16x8*)&As[(arow0 + m * 16) * 104 + ks * 32 + kg];
        #pragma unroll
        for (int n = 0; n < 4; ++n)
            bfr[n] = *(const s16x8*)&Bs[(bcol0 + n * 16) * 104 + ks * 32 + kg];
        #pragma unroll
        for (int m = 0; m < 8; ++m)
            #pragma unroll
            for (int n = 0; n < 4; ++n)
                acc[m][n] = __builtin_amdgcn_mfma_f32_16x16x32_bf16(af[m], bfr[n], acc[m][n], 0, 0, 0);
    }

    // --- per-column stats over the 256 segment rows ---
    float s[4], q[4];
    #pragma unroll
    for (int n = 0; n < 4; ++n) { s[n] = 0.f; q[n] = 0.f; }
    #pragma unroll
    for (int m = 0; m < 8; ++m)
        #pragma unroll
        for (int n = 0; n < 4; ++n)
            #pragma unroll
            for (int j = 0; j < 4; ++j) { float v = acc[m][n][j]; s[n] += v; q[n] += v * v; }
    #pragma unroll
    for (int n = 0; n < 4; ++n) {
        s[n] += __shfl_xor(s[n], 16); q[n] += __shfl_xor(q[n], 16);
        s[n] += __shfl_xor(s[n], 32); q[n] += __shfl_xor(q[n], 32);
    }
    if ((lane >> 4) == 0) {
        #pragma unroll
        for (int n = 0; n < 4; ++n) { statsS[wid][n][lane] = s[n]; statsQ[wid][n][lane] = q[n]; }
    }
    __syncthreads();

    const float inv256 = 1.0f / 256.0f;
    float aa[4], bb[4];
    const int c16 = lane & 15;
    #pragma unroll
    for (int n = 0; n < 4; ++n) {
        float sum = statsS[wc][n][c16] + statsS[4 + wc][n][c16];
        float sq  = statsQ[wc][n][c16] + statsQ[4 + wc][n][c16];
        float mean = sum * inv256;
        float var  = sq * inv256 - mean * mean;
        float rinv = rsqrtf(var + EPSB);
        int col = ct * 256 + wc * 64 + n * 16 + c16;
        aa[n] = g1[col] * rinv;
        bb[n] = be1[col] - mean * aa[n];
    }

    ushort* outp = h1 + (size_t)(seg * SEGROWS) * N1 + ct * 256;
    const int rbase = wr * 128 + (lane >> 4) * 4;
    #pragma unroll
    for (int m = 0; m < 8; ++m)
        #pragma unroll
        for (int j = 0; j < 4; ++j) {
            int r = rbase + m * 16 + j;
            ushort* rowp = outp + (size_t)r * N1 + wc * 64 + c16;
            #pragma unroll
            for (int n = 0; n < 4; ++n) {
                float v = acc[m][n][j] * aa[n] + bb[n];
                v = v > 0.f ? v : 0.f;
                rowp[n * 16] = f2bf(v);
            }
        }
}

// ==================== layer 2: 8-phase 256x256 template (T3+T4+T2+T5) ====================
// BK=64 (8 K-tiles of K=512), double-buffered LDS, 4 phases/tile x 16 MFMA/phase,
// ONE barrier per phase, ONE counted vmcnt per tile (never 0 until the tail).
//
// LDS per buffer: [256 rows][64 bf16], row stride 128B = 8 chunks of 16B.
// Swizzle: phys_chunk = logical_chunk ^ (row&7) -> every ds_read_b128 is
// bank-balanced (8 accesses/bank = minimum). global_load_lds writes linearly
// (rule #21), so the inverse XOR goes on the per-lane GLOBAL source chunk.
//
// SYNC INVARIANT (the round-2 bug was violating this): a ds_read of tile T's
// data must be program-after a barrier which is program-after the vmcnt that
// retires ALL of tile T's staging loads (in every wave; the barrier makes the
// per-wave vmcnt a block-wide guarantee).
//
// Staging (per tile U): q0: A1(U+1) | q1: B0(U+1) | q2: B1(U+1) | q3: A0(U+2).
// Per-thread queue at q3(U), oldest->newest (2 loads each):
//   A0(U+1)[q3(U-1)], A1(U+1)[q0(U)], B0(U+1)[q1(U)], B1(U+1)[q2(U)], A0(U+2)[q3(U)]
// vmcnt(2) at q3(U) retires the 8 oldest = ALL of tile U+1, leaves A0(U+2).
// Then BAR(q3(U)) -> tile U+1's reads (issued right after) are safe.
// Tail: q3(6) has no new stage (8 outstanding) -> vmcnt(0); tile 7 trivial.
// Prologue: stage A0/A1/B0/B1(0)+A0(1), vmcnt(2), barrier -> tile 0 safe.
//
// WAR (stage overwriting a slot still being read): every stage lands >=2
// barriers after the last ds_read of the slot's old contents completed
// (reads complete before the mfma that consumes them, which precedes the
// next barrier). a03 is register-held across q3, so its LDS slot is dead
// after q1. Leads: A0 4 phases, A1 3, B0 2, B1 1 -- the 1-phase half is B1
// (W2b, 1 MiB, L2-resident ~200cy), covered by one MFMA phase.

// stage one 128-row half (16KB) at k-window kt: 2 x gload_lds16 per thread.
static __device__ __forceinline__ void stage_half(
    const char* gsrc, char* ldst, int kt, int wid, int lane)
{
    const int row = (wid << 3) + (lane >> 3);      // 0..63 within an 8KB round
    const int cl  = (lane & 7) ^ (lane >> 3);      // inverse-swizzled source chunk
    const char* g = gsrc + (size_t)row * 1024 + (size_t)kt * 128 + cl * 16;
    gload_lds16(g,          ldst + wid * 1024);
    gload_lds16(g + 65536,  ldst + 8192 + wid * 1024);   // +64 rows
}

static __device__ __forceinline__ void read_a4(
    s16x8 (&dst)[4][2], const ushort* base, int arow0, int mofs, int ko0, int ko1)
{
    #pragma unroll
    for (int mi = 0; mi < 4; ++mi) {
        const ushort* p = base + (arow0 + (mofs + mi) * 16) * 64;
        dst[mi][0] = *(const s16x8*)(p + ko0);
        dst[mi][1] = *(const s16x8*)(p + ko1);
    }
}
static __device__ __forceinline__ void read_b2(
    s16x8 (&dst)[2][2], const ushort* base, int bcol0, int nofs, int ko0, int ko1)
{
    #pragma unroll
    for (int ni = 0; ni < 2; ++ni) {
        const ushort* p = base + (bcol0 + (nofs + ni) * 16) * 64;
        dst[ni][0] = *(const s16x8*)(p + ko0);
        dst[ni][1] = *(const s16x8*)(p + ko1);
    }
}
static __device__ __forceinline__ void mfma_q(
    f32x4 (&acc)[8][4], const s16x8 (&af)[4][2], const s16x8 (&bfr)[2][2],
    int mofs, int nofs)
{
    __builtin_amdgcn_s_setprio(1);
    #pragma unroll
    for (int mi = 0; mi < 4; ++mi)
        #pragma unroll
        for (int ni = 0; ni < 2; ++ni) {
            f32x4 c = acc[mofs + mi][nofs + ni];
            c = __builtin_amdgcn_mfma_f32_16x16x32_bf16(af[mi][0], bfr[ni][0], c, 0, 0, 0);
            c = __builtin_amdgcn_mfma_f32_16x16x32_bf16(af[mi][1], bfr[ni][1], c, 0, 0, 0);
            acc[mofs + mi][nofs + ni] = c;
        }
    __builtin_amdgcn_s_setprio(0);
}

// phase boundary: sched_barrier(0) pins register-only MFMA inside its phase
// (rule #18), asm "memory" stops any IR-level motion of ds_read/stage across
// the barrier (hoisting a read above it would break the sync invariant).
#define PHASE_BAR() do { __builtin_amdgcn_sched_barrier(0); \
    asm volatile("s_barrier" ::: "memory"); \
    __builtin_amdgcn_sched_barrier(0); } while (0)

__global__ __launch_bounds__(512, 2) void layer2_kernel(
    const ushort* __restrict__ h1, const ushort* __restrict__ W2b,
    const float* __restrict__ g2, const float* __restrict__ be2,
    float* __restrict__ out)
{
    __shared__ __align__(16) ushort Asl[2 * 256 * 64];   // 2 x 32 KiB (A0,A1 halves)
    __shared__ __align__(16) ushort Bsl[2 * 256 * 64];   // 2 x 32 KiB (B0,B1 halves)
    __shared__ float statsS[8][4][16];
    __shared__ float statsQ[8][4][16];

    // bijective XCD swizzle (nwg=4096 % 8 == 0): the 4 ct-blocks of a segment
    // run consecutively on one XCD -> h1 panel (256KB) hits L2 3 of 4 times.
    const int b   = blockIdx.x;
    const int wg  = (b & 7) * 512 + (b >> 3);
    const int seg = wg >> 2;
    const int ct  = wg & 3;

    const int tid  = threadIdx.x;
    const int lane = tid & 63, wid = tid >> 6;
    const int wr   = wid >> 2, wc = wid & 3;

    const char* srcA = (const char*)(h1  + (size_t)seg * SEGROWS * N1);
    const char* srcB = (const char*)(W2b + (size_t)ct  * 256    * N1);

    f32x4 acc[8][4] = {};
    const int arow0 = wr * 128 + (lane & 15);
    const int bcol0 = wc * 64  + (lane & 15);
    // logical 16B k-chunk = ks*4 + (lane>>4); fragment rows have row&7 == lane&7;
    // forward swizzle on the read side, in ushort units (chunk*8):
    const int ko0 = (((lane >> 4)    ) ^ (lane & 7)) * 8;
    const int ko1 = (((lane >> 4) + 4) ^ (lane & 7)) * 8;

    // prologue: A0(0) A1(0) B0(0) B1(0) A0(1)  (10 loads/thread)
    stage_half(srcA,          (char*)Asl,          0, wid, lane);
    stage_half(srcA + 131072, (char*)Asl + 16384,  0, wid, lane);
    stage_half(srcB,          (char*)Bsl,          0, wid, lane);
    stage_half(srcB + 131072, (char*)Bsl + 16384,  0, wid, lane);
    stage_half(srcA,          (char*)Asl + 32768,  1, wid, lane);
    asm volatile("s_waitcnt vmcnt(2)" ::: "memory");   // tile 0 landed; A0(1) in flight
    PHASE_BAR();

#define L2_TILE(U, VW)                                                              \
    {                                                                               \
        const ushort* Ab = Asl + ((U) & 1) * 16384;                                 \
        const ushort* Bb = Bsl + ((U) & 1) * 16384;                                 \
        char* Acur = (char*)Asl + ((U) & 1) * 32768;                                \
        char* An   = (char*)Asl + (((U) + 1) & 1) * 32768;                          \
        char* Bn   = (char*)Bsl + (((U) + 1) & 1) * 32768;                          \
        s16x8 a03[4][2], a47[4][2], b01[2][2], b23[2][2];                           \
        /* q0: read A m0-3 + B n0-1 (tile U confirmed at q3(U-1)); stage A1(U+1) */ \
        read_a4(a03, Ab, arow0, 0, ko0, ko1);                                       \
        read_b2(b01, Bb, bcol0, 0, ko0, ko1);                                       \
        if ((U) + 1 < 8) stage_half(srcA + 131072, An + 16384, (U) + 1, wid, lane); \
        PHASE_BAR();                                                                \
        mfma_q(acc, a03, b01, 0, 0);                                                \
        /* q1: read A m4-7; stage B0(U+1); MFMA (1,0)  [b01 held] */                \
        read_a4(a47, Ab, arow0, 4, ko0, ko1);                                       \
        if ((U) + 1 < 8) stage_half(srcB, Bn, (U) + 1, wid, lane);                  \
        PHASE_BAR();                                                                \
        mfma_q(acc, a47, b01, 4, 0);                                                \
        /* q2: read B n2-3; stage B1(U+1); MFMA (1,1)  [a47 held] */                \
        read_b2(b23, Bb, bcol0, 2, ko0, ko1);                                       \
        if ((U) + 1 < 8) stage_half(srcB + 131072, Bn + 16384, (U) + 1, wid, lane); \
        PHASE_BAR();                                                                \
        mfma_q(acc, a47, b23, 4, 2);                                                \
        /* q3: stage A0(U+2) over dead A0(U); vmcnt retires ALL of tile U+1;  */    \
        /*     barrier makes that block-wide; MFMA (0,1) [a03,b23 held]       */    \
        if ((U) + 2 < 8) stage_half(srcA, Acur, (U) + 2, wid, lane);                \
        asm volatile("s_waitcnt vmcnt(" #VW ")" ::: "memory");                      \
        PHASE_BAR();                                                                \
        mfma_q(acc, a03, b23, 0, 2);                                                \
    }

    L2_TILE(0, 2) L2_TILE(1, 2) L2_TILE(2, 2) L2_TILE(3, 2)
    L2_TILE(4, 2) L2_TILE(5, 2) L2_TILE(6, 0) L2_TILE(7, 0)
#undef L2_TILE

    // --- per-column stats over the 256 segment rows ---
    float s[4], q[4];
    #pragma unroll
    for (int n = 0; n < 4; ++n) { s[n] = 0.f; q[n] = 0.f; }
    #pragma unroll
    for (int m = 0; m < 8; ++m)
        #pragma unroll
        for (int n = 0; n < 4; ++n)
            #pragma unroll
            for (int j = 0; j < 4; ++j) { float v = acc[m][n][j]; s[n] += v; q[n] += v * v; }
    #pragma unroll
    for (int n = 0; n < 4; ++n) {
        s[n] += __shfl_xor(s[n], 16); q[n] += __shfl_xor(q[n], 16);
        s[n] += __shfl_xor(s[n], 32); q[n] += __shfl_xor(q[n], 32);
    }
    if ((lane >> 4) == 0) {
        #pragma unroll
        for (int n = 0; n < 4; ++n) { statsS[wid][n][lane] = s[n]; statsQ[wid][n][lane] = q[n]; }
    }
    __syncthreads();

    const float inv256 = 1.0f / 256.0f;
    float aa[4], bb[4];
    const int c16 = lane & 15;
    #pragma unroll
    for (int n = 0; n < 4; ++n) {
        float sum = statsS[wc][n][c16] + statsS[4 + wc][n][c16];
        float sq  = statsQ[wc][n][c16] + statsQ[4 + wc][n][c16];
        float mean = sum * inv256;
        float var  = sq * inv256 - mean * mean;
        float rinv = rsqrtf(var + EPSB);
        int col = ct * 256 + wc * 64 + n * 16 + c16;
        aa[n] = g2[col] * rinv;
        bb[n] = be2[col] - mean * aa[n];
    }

    float* outp = out + (size_t)(seg * SEGROWS) * N2 + ct * 256;
    const int rbase = wr * 128 + (lane >> 4) * 4;
    #pragma unroll
    for (int m = 0; m < 8; ++m)
        #pragma unroll
        for (int j = 0; j < 4; ++j) {
            int r = rbase + m * 16 + j;
            float* rowp = outp + (size_t)r * N2 + wc * 64 + c16;
            #pragma unroll
            for (int n = 0; n < 4; ++n) {
                float v = acc[m][n][j] * aa[n] + bb[n];
                v = v > 0.f ? v : 0.f;
                rowp[n * 16] = v;
            }
        }
}

extern "C" void kernel_launch(void* const* d_in, const int* in_sizes, int n_in,
                              void* d_out, int out_size, void* d_ws, size_t ws_size,
                              hipStream_t stream) {
    const float* hstate = (const float*)d_in[0];
    const float* ebpr   = (const float*)d_in[1];
    const float* Wsp    = (const float*)d_in[2];
    // d_in[3] = b_sp  : cancels through segment BN (exact)
    const float* W1     = (const float*)d_in[4];
    // d_in[5] = b1    : cancels through segment BN (exact)
    const float* g1     = (const float*)d_in[6];
    const float* be1    = (const float*)d_in[7];
    const float* W2     = (const float*)d_in[8];
    // d_in[9] = b2    : cancels through segment BN (exact)
    const float* g2     = (const float*)d_in[10];
    const float* be2    = (const float*)d_in[11];
    float* outp         = (float*)d_out;

    ushort* h1  = (ushort*)d_ws;                          // 262144 x 512 bf16 = 256 MiB
    ushort* W2b = h1 + (size_t)TOTALROWS * N1;            // 1024 x 512 bf16 = 1 MiB

    convert_w2_kernel<<<dim3((N2 * N1 / 4) / 256), dim3(256), 0, stream>>>(W2, W2b);
    layer1_kernel<<<dim3(NSEG, 2), dim3(512), 0, stream>>>(hstate, ebpr, Wsp, W1, g1, be1, h1);
    layer2_kernel<<<dim3(4096), dim3(512), 0, stream>>>(h1, W2b, g2, be2, outp);
}